// Round 6
// baseline (1358.985 us; speedup 1.0000x reference)
//
#include <hip/hip_runtime.h>
#include <math.h>

// ---------------------------------------------------------------------------
// WaveletNet forward. Big convs via f16 MFMA implicit GEMM:
//  - conv_mfma4: m97-style 128x128x32 tile, split-K=3 (grid 768 = 3 blocks/CU),
//    f16 partials + reduce3 (bias/add/lrelu fused).
//  - conv_mfma2: 128x64x64 single-buffer for the BN=64 shapes.
// Small convs direct fp32. GN split 3-kernel. N=16 fixed.
// ---------------------------------------------------------------------------

#define NB 16  // batch

typedef _Float16 f16;
typedef _Float16 f16x8 __attribute__((ext_vector_type(8)));
typedef _Float16 f16x4 __attribute__((ext_vector_type(4)));
typedef float f32x4 __attribute__((ext_vector_type(4)));
typedef unsigned int u32;

// async global->LDS 16B: lds dest must be wave-uniform base (+lane*16 by HW)
#define LLDS16(gp, lp)                                                          \
  __builtin_amdgcn_global_load_lds((const __attribute__((address_space(1))) u32*)(const void*)(gp), \
                                   (__attribute__((address_space(3))) u32*)(void*)(lp), 16, 0, 0)

// ---------------- weight standardization (fp32 out, for direct convs) -------
__global__ void ws_kernel(const float* __restrict__ w, float* __restrict__ out, int fan) {
  __shared__ float red[512];
  int o = blockIdx.x;
  const float* wp = w + (size_t)o * fan;
  float s = 0.f, s2 = 0.f;
  for (int i = threadIdx.x; i < fan; i += 256) { float v = wp[i]; s += v; s2 += v * v; }
  red[threadIdx.x] = s; red[256 + threadIdx.x] = s2;
  __syncthreads();
  for (int st = 128; st > 0; st >>= 1) {
    if (threadIdx.x < st) {
      red[threadIdx.x] += red[threadIdx.x + st];
      red[256 + threadIdx.x] += red[256 + threadIdx.x + st];
    }
    __syncthreads();
  }
  float sum = red[0], sumsq = red[256];
  float mean = sum / (float)fan;
  float var = (sumsq - sum * mean) / (float)(fan - 1);
  if (var < 0.f) var = 0.f;
  float inv = 1.0f / (sqrtf(var) + 1e-5f);
  for (int i = threadIdx.x; i < fan; i += 256)
    out[(size_t)o * fan + i] = (wp[i] - mean) * inv;
}

// ---------------- weight standardization + f16 pack [tap][Cout][Cin] --------
__global__ void ws_f16_kernel(const float* __restrict__ w, f16* __restrict__ out,
                              int fan, int Cin, int Cout) {
  __shared__ float red[512];
  int o = blockIdx.x;
  const float* wp = w + (size_t)o * fan;
  float s = 0.f, s2 = 0.f;
  for (int i = threadIdx.x; i < fan; i += 256) { float v = wp[i]; s += v; s2 += v * v; }
  red[threadIdx.x] = s; red[256 + threadIdx.x] = s2;
  __syncthreads();
  for (int st = 128; st > 0; st >>= 1) {
    if (threadIdx.x < st) {
      red[threadIdx.x] += red[threadIdx.x + st];
      red[256 + threadIdx.x] += red[256 + threadIdx.x + st];
    }
    __syncthreads();
  }
  float sum = red[0], sumsq = red[256];
  float mean = sum / (float)fan;
  float var = (sumsq - sum * mean) / (float)(fan - 1);
  if (var < 0.f) var = 0.f;
  float inv = 1.0f / (sqrtf(var) + 1e-5f);
  for (int i = threadIdx.x; i < fan; i += 256) {
    int ci = i / 9, tap = i - ci * 9;
    out[((size_t)tap * Cout + o) * Cin + ci] = (f16)((wp[i] - mean) * inv);
  }
}

// ---------------- zero the 1-px halo of a padded NHWC f16 buffer ------------
__global__ void zero_halo_kernel(f16* __restrict__ buf, int C, int H, int W, int total8) {
  int idx = blockIdx.x * 256 + threadIdx.x;
  if (idx >= total8) return;
  int c8s = C >> 3;
  int c8 = idx % c8s; int t = idx / c8s;
  int P = 2 * (W + 2) + 2 * H;
  int b = t % P; int n = t / P;
  int y, x;
  if (b < W + 2) { y = 0; x = b; }
  else if (b < 2 * (W + 2)) { y = H + 1; x = b - (W + 2); }
  else { int bb = b - 2 * (W + 2); y = 1 + (bb >> 1); x = (bb & 1) ? (W + 1) : 0; }
  size_t a = (((size_t)n * (H + 2) + y) * (W + 2) + x) * C + c8 * 8;
  f16x8 z = {0, 0, 0, 0, 0, 0, 0, 0};
  *(f16x8*)(buf + a) = z;
}

// ---------------- NCHW fp32 -> padded NHWC f16 transpose ----------------
__global__ __launch_bounds__(256) void to_nhwc_pad_kernel(const float* __restrict__ in,
                                                          f16* __restrict__ out,
                                                          int C, int H, int W) {
  __shared__ f16 sm[32][264];
  int HW = H * W;
  int p0 = blockIdx.x * 256, c0 = blockIdx.y * 32, n = blockIdx.z;
  int t = threadIdx.x;
  const float* ip = in + ((size_t)n * C + c0) * HW + p0;
#pragma unroll 8
  for (int r = 0; r < 32; ++r) sm[r][t] = (f16)ip[(size_t)r * HW + t];
  __syncthreads();
#pragma unroll
  for (int i = 0; i < 4; ++i) {
    int c = t + i * 256;
    int pl = c >> 2, cio = (c & 3) * 8;
    f16x8 v;
#pragma unroll
    for (int u = 0; u < 8; ++u) v[u] = sm[cio + u][pl];
    int p = p0 + pl; int y = p / W; int x = p - y * W;
    *(f16x8*)(out + (((size_t)n * (H + 2) + y + 1) * (W + 2) + x + 1) * C + c0 + cio) = v;
  }
}

// ---------------- conv_mfma4: m97-style 128x128x32, split-K over gridDim.z --
// A: padded NHWC f16. Wp: [9][Cout][Cin]. part: f16 partials [S][N][Cout][HW].
// 4 waves 2x2, wave tile 64x64 (4x4 of 16x16), single LDS buffer, 2 barriers.
// LDS layout [kchunk(4)][row(128)] of 16B chunks -> benign 2-way banking.
__global__ __launch_bounds__(256) void conv_mfma4_kernel(
    const f16* __restrict__ A, const f16* __restrict__ Wp,
    f16* __restrict__ part, int Cin, int H, int W, int Cout, int HW) {
  __shared__ f16 Asm[128 * 32];  // 8 KB
  __shared__ f16 Bsm[128 * 32];  // 8 KB

  const int tid = threadIdx.x;
  const int w = tid >> 6, lane = tid & 63;
  const int m0 = blockIdx.x * 128;
  const int co0 = blockIdx.y * 128;
  const int Wp2 = W + 2;

  // staging: 512 chunks each for A and B, 2 issues/thread
  const f16* gA[2]; const f16* gB[2];
#pragma unroll
  for (int e = 0; e < 2; ++e) {
    int c = e * 256 + tid;
    int r = c & 127, j = c >> 7;
    int m = m0 + r; int n = m / HW; int p = m - n * HW;
    int y = p / W; int x = p - y * W;
    gA[e] = A + (((size_t)n * (H + 2) + y + 1) * Wp2 + (x + 1)) * Cin + j * 8;
    gB[e] = Wp + (size_t)(co0 + r) * Cin + j * 8;
  }
  const int ldsw = w * 64 * 8;  // wave-uniform; lane adds lane*16B

  const int wm = w & 1, wn = w >> 1;
  const int lr = lane & 15, quad = lane >> 4;
  int aoffs[4], boffs[4];
#pragma unroll
  for (int i = 0; i < 4; ++i) {
    aoffs[i] = (quad * 128 + wm * 64 + i * 16 + lr) * 8;
    boffs[i] = (quad * 128 + wn * 64 + i * 16 + lr) * 8;
  }

  f32x4 acc[4][4];
#pragma unroll
  for (int i = 0; i < 4; ++i)
#pragma unroll
    for (int j = 0; j < 4; ++j) acc[i][j] = (f32x4){0.f, 0.f, 0.f, 0.f};

  const int kpt = Cin >> 5;                 // 32-chunks per tap
  const int nit = (9 * kpt) / gridDim.z;    // iterations per split
  const int it0 = blockIdx.z * nit;
  const size_t bstride = (size_t)Cout * Cin;

  for (int ii = 0; ii < nit; ++ii) {
    int it = it0 + ii;
    int tap = it / kpt, kk = it - tap * kpt;
    int dy = tap / 3 - 1, dx = tap % 3 - 1;
    long offA = ((long)dy * Wp2 + dx) * Cin + (kk << 5);
    long offB = (long)tap * bstride + (kk << 5);
    __syncthreads();  // prior reads complete before overwrite
#pragma unroll
    for (int e = 0; e < 2; ++e) {
      LLDS16(gA[e] + offA, Asm + e * 2048 + ldsw);
      LLDS16(gB[e] + offB, Bsm + e * 2048 + ldsw);
    }
    __syncthreads();  // staging visible (compiler drains vmcnt)

    f16x8 af[4], bf[4];
#pragma unroll
    for (int i = 0; i < 4; ++i) af[i] = *(const f16x8*)&Asm[aoffs[i]];
#pragma unroll
    for (int j = 0; j < 4; ++j) bf[j] = *(const f16x8*)&Bsm[boffs[j]];
#pragma unroll
    for (int i = 0; i < 4; ++i)
#pragma unroll
      for (int j = 0; j < 4; ++j)
        acc[i][j] = __builtin_amdgcn_mfma_f32_16x16x32_f16(af[i], bf[j], acc[i][j], 0, 0, 0);
  }

  // epilogue: f16 partial, rows = quad*4+reg, col = lr
  const size_t pbase = (size_t)blockIdx.z * NB * Cout * HW;
#pragma unroll
  for (int i = 0; i < 4; ++i) {
    int mg = m0 + wm * 64 + i * 16 + quad * 4;
    int n = mg / HW, p = mg - n * HW;
#pragma unroll
    for (int j = 0; j < 4; ++j) {
      int co = co0 + wn * 64 + j * 16 + lr;
      f32x4 v = acc[i][j];
      f16x4 h;
#pragma unroll
      for (int r = 0; r < 4; ++r) h[r] = (f16)v[r];
      *(f16x4*)&part[pbase + ((size_t)n * Cout + co) * HW + p] = h;
    }
  }
}

// ---------------- reduce 3 partials + bias (+add) (+lrelu) -> fp32 ----------
__global__ __launch_bounds__(256) void reduce3_kernel(
    const f16* __restrict__ part, const float* __restrict__ bias,
    const float* __restrict__ add, float* __restrict__ out,
    int Cout, int HW, int do_lrelu, int total4) {
  int idx = blockIdx.x * 256 + threadIdx.x;
  if (idx >= total4) return;
  size_t sstride = (size_t)NB * Cout * HW;
  int hw4 = HW >> 2;
  int p4 = idx % hw4; int t = idx / hw4;  // t = n*Cout + c
  int c = t % Cout;
  size_t eoff = (size_t)t * HW + p4 * 4;
  f16x4 a0 = *(const f16x4*)(part + eoff);
  f16x4 a1 = *(const f16x4*)(part + sstride + eoff);
  f16x4 a2 = *(const f16x4*)(part + 2 * sstride + eoff);
  float b = bias[c];
  f32x4 o;
#pragma unroll
  for (int r = 0; r < 4; ++r) o[r] = (float)a0[r] + (float)a1[r] + (float)a2[r] + b;
  if (add) {
    f32x4 av = *(const f32x4*)(add + eoff);
#pragma unroll
    for (int r = 0; r < 4; ++r) o[r] += av[r];
  }
  if (do_lrelu)
#pragma unroll
    for (int r = 0; r < 4; ++r) o[r] = o[r] > 0.f ? o[r] : 0.2f * o[r];
  *(f32x4*)(out + eoff) = o;
}

// ---------------- conv_mfma2: 128x64x64 single-buffer (BN=64 shapes) --------
__global__ __launch_bounds__(256) void conv_mfma2_kernel(
    const f16* __restrict__ A, const f16* __restrict__ Wp,
    const float* __restrict__ bias, float* __restrict__ out,
    int Cin, int H, int W, int Cout, int HW, int do_lrelu) {
  constexpr int BM = 128, BN = 64, BK = 64;
  __shared__ f16 Asm[BM * BK];
  __shared__ f16 Bsm[BN * BK];

  const int tid = threadIdx.x;
  const int w = tid >> 6, lane = tid & 63;
  const int m0 = blockIdx.x * BM;
  const int co0 = blockIdx.y * BN;
  const int Wp2 = W + 2;

  const f16* gA[4];
  int lAoff[4];
#pragma unroll
  for (int e = 0; e < 4; ++e) {
    int c = e * 256 + tid;
    int r = c >> 3, j = c & 7;
    int jx = j ^ (r & 7);
    int m = m0 + r; int n = m / HW; int p = m - n * HW;
    int y = p / W; int x = p - y * W;
    gA[e] = A + (((size_t)n * (H + 2) + y + 1) * Wp2 + (x + 1)) * Cin + jx * 8;
    lAoff[e] = (e * 256 + w * 64) * 8;
  }
  const f16* gB[2];
  int lBoff[2];
#pragma unroll
  for (int e = 0; e < 2; ++e) {
    int c = e * 256 + tid;
    int r = c >> 3, j = c & 7;
    int jx = j ^ (r & 7);
    gB[e] = Wp + (size_t)(co0 + r) * Cin + jx * 8;
    lBoff[e] = (e * 256 + w * 64) * 8;
  }

  const int wm = w & 1, wn = w >> 1;
  const int lr = lane & 15, quad = lane >> 4;
  int aoffs[4][2], boffs[2][2];
#pragma unroll
  for (int i = 0; i < 4; ++i)
#pragma unroll
    for (int kk = 0; kk < 2; ++kk) {
      int r = wm * 64 + i * 16 + lr;
      int cidx = kk * 4 + quad;
      aoffs[i][kk] = (r * 8 + (cidx ^ (r & 7))) * 8;
    }
#pragma unroll
  for (int jn = 0; jn < 2; ++jn)
#pragma unroll
    for (int kk = 0; kk < 2; ++kk) {
      int rb = wn * 32 + jn * 16 + lr;
      int cidx = kk * 4 + quad;
      boffs[jn][kk] = (rb * 8 + (cidx ^ (rb & 7))) * 8;
    }

  f32x4 acc[4][2];
#pragma unroll
  for (int i = 0; i < 4; ++i)
#pragma unroll
    for (int jn = 0; jn < 2; ++jn) acc[i][jn] = (f32x4){0.f, 0.f, 0.f, 0.f};

  for (int tap = 0; tap < 9; ++tap) {
    const int dy = tap / 3 - 1, dx = tap % 3 - 1;
    const long tapA = ((long)dy * Wp2 + dx) * Cin;
    const long tapB = (size_t)tap * Cout * Cin;
    for (int kc = 0; kc < Cin; kc += BK) {
      __syncthreads();
#pragma unroll
      for (int e = 0; e < 4; ++e) LLDS16(gA[e] + tapA + kc, Asm + lAoff[e]);
#pragma unroll
      for (int e = 0; e < 2; ++e) LLDS16(gB[e] + tapB + kc, Bsm + lBoff[e]);
      __syncthreads();

      f16x8 af[4][2], bf[2][2];
#pragma unroll
      for (int i = 0; i < 4; ++i)
#pragma unroll
        for (int kk = 0; kk < 2; ++kk) af[i][kk] = *(const f16x8*)&Asm[aoffs[i][kk]];
#pragma unroll
      for (int jn = 0; jn < 2; ++jn)
#pragma unroll
        for (int kk = 0; kk < 2; ++kk) bf[jn][kk] = *(const f16x8*)&Bsm[boffs[jn][kk]];
#pragma unroll
      for (int kk = 0; kk < 2; ++kk)
#pragma unroll
        for (int i = 0; i < 4; ++i)
#pragma unroll
          for (int jn = 0; jn < 2; ++jn)
            acc[i][jn] = __builtin_amdgcn_mfma_f32_16x16x32_f16(af[i][kk], bf[jn][kk], acc[i][jn], 0, 0, 0);
    }
  }

#pragma unroll
  for (int i = 0; i < 4; ++i) {
    int mg = m0 + wm * 64 + i * 16 + quad * 4;
    int n = mg / HW, p = mg - n * HW;
#pragma unroll
    for (int jn = 0; jn < 2; ++jn) {
      int co = co0 + wn * 32 + jn * 16 + lr;
      float b = bias[co];
      f32x4 v = acc[i][jn];
#pragma unroll
      for (int r = 0; r < 4; ++r) {
        float u = v[r] + b;
        v[r] = (do_lrelu && u < 0.f) ? 0.2f * u : u;
      }
      *(f32x4*)&out[((size_t)n * Cout + co) * HW + p] = v;
    }
  }
}

// ---------------- Haar forward (wt) ----------------
__global__ void wt_kernel(const float* __restrict__ in, float* __restrict__ out,
                          int C, int Ho, int Wo, int total) {
  int idx = blockIdx.x * 256 + threadIdx.x;
  if (idx >= total) return;
  int w = idx % Wo; int t = idx / Wo;
  int h = t % Ho; t /= Ho;
  int c = t % C; int n = t / C;
  int Wi = 2 * Wo;
  const float* ip = in + (((size_t)n * C + c) * (2 * Ho) + 2 * h) * Wi + 2 * w;
  float a = ip[0], b = ip[1], cc = ip[Wi], d = ip[Wi + 1];
  size_t cs = (size_t)Ho * Wo;
  float* op = out + (((size_t)n * 4 * C + 4 * c) * Ho + h) * Wo + w;
  op[0]      = 0.25f * (a + b + cc + d);
  op[cs]     = 0.25f * (a + b - cc - d) + 0.5f;
  op[2 * cs] = 0.25f * (a - b + cc - d) + 0.5f;
  op[3 * cs] = 0.25f * (a - b - cc + d) + 0.5f;
}

// ---------------- Haar inverse (iwt) ----------------
__global__ void iwt_kernel(const float* __restrict__ v, float* __restrict__ out,
                           int C, int H, int W, int c_off, int Ctot, int total) {
  int idx = blockIdx.x * 256 + threadIdx.x;
  if (idx >= total) return;
  int w = idx % W; int t = idx / W;
  int h = t % H; t /= H;
  int c = t % C; int n = t / C;
  size_t cs = (size_t)H * W;
  const float* vp = v + (((size_t)n * 4 * C + 4 * c) * H + h) * W + w;
  float v0 = vp[0];
  float v1 = 2.f * vp[cs] - 1.f;
  float v2 = 2.f * vp[2 * cs] - 1.f;
  float v3 = 2.f * vp[3 * cs] - 1.f;
  int Wo = 2 * W;
  float* op = out + (((size_t)n * Ctot + c_off + c) * (2 * H) + 2 * h) * (size_t)Wo + 2 * w;
  op[0]      = v0 + 0.5f * ( v1 + v2 + v3);
  op[1]      = v0 + 0.5f * ( v1 - v2 - v3);
  op[Wo]     = v0 + 0.5f * (-v1 + v2 - v3);
  op[Wo + 1] = v0 + 0.5f * (-v1 - v2 + v3);
}

// ---------------- concat first-part copy ----------------
__global__ void copycat_kernel(const float* __restrict__ src, float* __restrict__ dst,
                               int C, int HW, int Ctot, int total) {
  int idx = blockIdx.x * 256 + threadIdx.x;
  if (idx >= total) return;
  int p = idx % HW; int t = idx / HW;
  int c = t % C; int n = t / C;
  dst[((size_t)n * Ctot + c) * HW + p] = src[idx];
}

// ---------------- direct 3x3 conv (small channel counts) ----------------
template <int CO, int CIC>
__global__ __launch_bounds__(256) void conv3x3_kernel(
    const float* __restrict__ in, const float* __restrict__ wgt,
    const float* __restrict__ bias, float* __restrict__ out,
    int Cin, int H, int W, int Cout, int do_lrelu) {
  __shared__ float sm[CIC][18][18];
  int tiles_x = W >> 4;
  int bt = blockIdx.x;
  int tx0 = (bt % tiles_x) << 4;
  int ty0 = (bt / tiles_x) << 4;
  int co0 = blockIdx.y * CO;
  int n = blockIdx.z;
  int tid = threadIdx.x;
  int lx = tid & 15, ly = tid >> 4;

  float acc[CO];
#pragma unroll
  for (int i = 0; i < CO; i++) acc[i] = 0.f;

  const float* inb = in + (size_t)n * Cin * H * W;

  for (int ci0 = 0; ci0 < Cin; ci0 += CIC) {
    __syncthreads();
    for (int idx = tid; idx < CIC * 324; idx += 256) {
      int ci = idx / 324;
      int r = idx - ci * 324;
      int gy = r / 18, gx = r - gy * 18;
      int iy = ty0 + gy - 1, ix = tx0 + gx - 1;
      float v = 0.f;
      if ((unsigned)iy < (unsigned)H && (unsigned)ix < (unsigned)W)
        v = inb[((size_t)(ci0 + ci)) * H * W + (size_t)iy * W + ix];
      sm[ci][gy][gx] = v;
    }
    __syncthreads();
#pragma unroll
    for (int ci = 0; ci < CIC; ci++) {
      float x00 = sm[ci][ly][lx],     x01 = sm[ci][ly][lx + 1],     x02 = sm[ci][ly][lx + 2];
      float x10 = sm[ci][ly + 1][lx], x11 = sm[ci][ly + 1][lx + 1], x12 = sm[ci][ly + 1][lx + 2];
      float x20 = sm[ci][ly + 2][lx], x21 = sm[ci][ly + 2][lx + 1], x22 = sm[ci][ly + 2][lx + 2];
      const float* wp = wgt + ((size_t)co0 * Cin + (ci0 + ci)) * 9;
#pragma unroll
      for (int co = 0; co < CO; co++) {
        const float* wc = wp + (size_t)co * Cin * 9;
        float a = acc[co];
        a = fmaf(wc[0], x00, a); a = fmaf(wc[1], x01, a); a = fmaf(wc[2], x02, a);
        a = fmaf(wc[3], x10, a); a = fmaf(wc[4], x11, a); a = fmaf(wc[5], x12, a);
        a = fmaf(wc[6], x20, a); a = fmaf(wc[7], x21, a); a = fmaf(wc[8], x22, a);
        acc[co] = a;
      }
    }
  }

  int oy = ty0 + ly, ox = tx0 + lx;
#pragma unroll
  for (int co = 0; co < CO; co++) {
    float v = acc[co] + bias[co0 + co];
    if (do_lrelu) v = v > 0.f ? v : 0.2f * v;
    out[(((size_t)n * Cout + co0 + co) * H + oy) * W + ox] = v;
  }
}

// ---------------- group norm: split 3-kernel ----------------
__global__ __launch_bounds__(256) void gn_stats_kernel(const float* __restrict__ x,
                                                       float* __restrict__ part,
                                                       int C, int HW, int G, int SPLIT) {
  __shared__ float red[512];
  int gs = blockIdx.x;
  int g = gs / SPLIT, s = gs - g * SPLIT;
  int n = blockIdx.y;
  int cpg = C / G;
  int len = cpg * HW;
  int chunk = len / SPLIT;
  size_t base = ((size_t)n * C + (size_t)g * cpg) * HW + (size_t)s * chunk;
  const f32x4* xp = (const f32x4*)(x + base);
  int chunk4 = chunk >> 2;
  float sm = 0.f, s2 = 0.f;
  for (int i = threadIdx.x; i < chunk4; i += 256) {
    f32x4 v = xp[i];
    sm += v.x + v.y + v.z + v.w;
    s2 += v.x * v.x + v.y * v.y + v.z * v.z + v.w * v.w;
  }
  red[threadIdx.x] = sm; red[256 + threadIdx.x] = s2;
  __syncthreads();
  for (int st = 128; st > 0; st >>= 1) {
    if (threadIdx.x < st) {
      red[threadIdx.x] += red[threadIdx.x + st];
      red[256 + threadIdx.x] += red[256 + threadIdx.x + st];
    }
    __syncthreads();
  }
  if (threadIdx.x == 0) {
    int o = ((n * G + g) * SPLIT + s) * 2;
    part[o] = red[0]; part[o + 1] = red[256];
  }
}

__global__ void gn_combine_kernel(const float* __restrict__ part, float* __restrict__ stats,
                                  int SPLIT, int len, int total) {
  int idx = blockIdx.x * 256 + threadIdx.x;
  if (idx >= total) return;
  float s = 0.f, s2 = 0.f;
  for (int i = 0; i < SPLIT; ++i) { s += part[(idx * SPLIT + i) * 2]; s2 += part[(idx * SPLIT + i) * 2 + 1]; }
  float mean = s / (float)len;
  float var = s2 / (float)len - mean * mean;
  if (var < 0.f) var = 0.f;
  stats[idx * 2] = mean;
  stats[idx * 2 + 1] = rsqrtf(var + 1e-5f);
}

__global__ __launch_bounds__(256) void gn_apply_kernel(float* __restrict__ x,
                                                       const float* __restrict__ stats,
                                                       const float* __restrict__ gamma,
                                                       const float* __restrict__ beta,
                                                       int C, int HW, int G, int total4) {
  int idx = blockIdx.x * 256 + threadIdx.x;
  if (idx >= total4) return;
  int hw4 = HW >> 2;
  int p4 = idx % hw4; int t = idx / hw4;
  int c = t % C; int n = t / C;
  int cpg = C / G; int g = c / cpg;
  float mean = stats[(n * G + g) * 2];
  float inv  = stats[(n * G + g) * 2 + 1];
  float ga = gamma[c], be = beta[c];
  f32x4* xp = (f32x4*)(x + ((size_t)t * HW)) + p4;
  f32x4 v = *xp;
#pragma unroll
  for (int r = 0; r < 4; ++r) v[r] = (v[r] - mean) * inv * ga + be;
  *xp = v;
}

// ---------------- final 1x1 conv ----------------
__global__ void final_conv_kernel(const float* __restrict__ in, const float* __restrict__ w,
                                  float* __restrict__ out, int HW, int total) {
  int idx = blockIdx.x * 256 + threadIdx.x;
  if (idx >= total) return;
  int p = idx % HW; int n = idx / HW;
  const float* ip = in + (size_t)n * 3 * HW + p;
  float a = ip[0], b = ip[HW], c = ip[2 * (size_t)HW];
  float* op = out + (size_t)n * 2 * HW + p;
  op[0]  = w[0] * a + w[1] * b + w[2] * c;
  op[HW] = w[3] * a + w[4] * b + w[5] * c;
}

// ---------------------------------------------------------------------------

extern "C" void kernel_launch(void* const* d_in, const int* in_sizes, int n_in,
                              void* d_out, int out_size, void* d_ws, size_t ws_size,
                              hipStream_t stream) {
  const float* x        = (const float*)d_in[0];
  const float* conv1_w  = (const float*)d_in[1];
  const float* conv1_b  = (const float*)d_in[2];
  const float* conv2_w  = (const float*)d_in[3];
  const float* conv2_b  = (const float*)d_in[4];
  const float* conv3_w  = (const float*)d_in[5];
  const float* conv3_b  = (const float*)d_in[6];
  const float* conv4_w  = (const float*)d_in[7];
  const float* conv4_b  = (const float*)d_in[8];
  const float* convd1_w = (const float*)d_in[9];
  const float* convd1_b = (const float*)d_in[10];
  const float* convd2_w = (const float*)d_in[11];
  const float* convd2_b = (const float*)d_in[12];
  const float* convd3_w = (const float*)d_in[13];
  const float* convd3_b = (const float*)d_in[14];
  const float* convd4_w = (const float*)d_in[15];
  const float* convd4_b = (const float*)d_in[16];
  const float* final_w  = (const float*)d_in[17];
  const float* gn1_w = (const float*)d_in[18];
  const float* gn1_b = (const float*)d_in[19];
  const float* gn2_w = (const float*)d_in[20];
  const float* gn2_b = (const float*)d_in[21];
  const float* gn3_w = (const float*)d_in[22];
  const float* gn3_b = (const float*)d_in[23];
  const float* gn4_w = (const float*)d_in[24];
  const float* gn4_b = (const float*)d_in[25];

  char* base = (char*)d_ws;
  size_t off = 0;
  auto allocB = [&](size_t bytes) { size_t o = off; off = (off + bytes + 255) & ~(size_t)255; return o; };

  size_t o_sw1  = allocB(16 * 108 * 4);
  size_t o_swd1 = allocB(12 * 144 * 4);
  size_t o_swd2 = allocB(16 * 288 * 4);
  size_t o_swf  = allocB(6 * 4);
  size_t o_pw2  = allocB((size_t)9 * 64 * 64 * 2);
  size_t o_pw3  = allocB((size_t)9 * 256 * 256 * 2);
  size_t o_pw4  = allocB((size_t)9 * 1024 * 1024 * 2);
  size_t o_pwd3 = allocB((size_t)9 * 64 * 128 * 2);
  size_t o_pwd4 = allocB((size_t)9 * 256 * 512 * 2);
  size_t o_ah   = allocB((size_t)16 * 34 * 34 * 512 * 2);
  size_t o_part = allocB((size_t)3 * NB * 1024 * 256 * 2);  // f16 split-K partials (25.2 MB)
  size_t o_gnp  = allocB(4096 * 4);
  size_t o_gns  = allocB(4096 * 4);
  size_t o_c1 = allocB((size_t)NB * 16 * 128 * 128 * 4);
  size_t o_c2 = allocB((size_t)NB * 64 * 64 * 64 * 4);
  size_t o_c3 = allocB((size_t)NB * 256 * 32 * 32 * 4);
  size_t o_w4 = allocB((size_t)NB * 1024 * 16 * 16 * 4);
  size_t o_t1 = allocB((size_t)NB * 1024 * 16 * 16 * 4);
  size_t o_t2 = allocB((size_t)NB * 512 * 32 * 32 * 4);

  if (off > ws_size) return;

  float* c1 = (float*)(base + o_c1);
  float* c2 = (float*)(base + o_c2);
  float* c3 = (float*)(base + o_c3);
  float* w4 = (float*)(base + o_w4);
  float* t1 = (float*)(base + o_t1);
  float* t2 = (float*)(base + o_t2);
  f16* ah = (f16*)(base + o_ah);
  f16* part = (f16*)(base + o_part);
  f16* pw2 = (f16*)(base + o_pw2);
  f16* pw3 = (f16*)(base + o_pw3);
  f16* pw4 = (f16*)(base + o_pw4);
  f16* pwd3 = (f16*)(base + o_pwd3);
  f16* pwd4 = (f16*)(base + o_pwd4);
  float* gnp = (float*)(base + o_gnp);
  float* gns = (float*)(base + o_gns);

  // ---- weight prep ----
  ws_kernel<<<16, 256, 0, stream>>>(conv1_w,  (float*)(base + o_sw1),  108);
  ws_kernel<<<12, 256, 0, stream>>>(convd1_w, (float*)(base + o_swd1), 144);
  ws_kernel<<<16, 256, 0, stream>>>(convd2_w, (float*)(base + o_swd2), 288);
  ws_kernel<<<2,  256, 0, stream>>>(final_w,  (float*)(base + o_swf),  3);
  ws_f16_kernel<<<64,   256, 0, stream>>>(conv2_w,  pw2,  576,  64,   64);
  ws_f16_kernel<<<256,  256, 0, stream>>>(conv3_w,  pw3,  2304, 256,  256);
  ws_f16_kernel<<<1024, 256, 0, stream>>>(conv4_w,  pw4,  9216, 1024, 1024);
  ws_f16_kernel<<<64,   256, 0, stream>>>(convd3_w, pwd3, 1152, 128,  64);
  ws_f16_kernel<<<256,  256, 0, stream>>>(convd4_w, pwd4, 4608, 512,  256);

  auto launch_wt = [&](const float* in, float* out, int C, int Ho, int Wo) {
    int total = NB * C * Ho * Wo;
    wt_kernel<<<(total + 255) / 256, 256, 0, stream>>>(in, out, C, Ho, Wo, total);
  };
  auto prep_nhwc = [&](const float* in, int C, int H, int W) {
    int total8 = NB * (2 * (W + 2) + 2 * H) * (C / 8);
    zero_halo_kernel<<<(total8 + 255) / 256, 256, 0, stream>>>(ah, C, H, W, total8);
    dim3 g((H * W) / 256, C / 32, NB);
    to_nhwc_pad_kernel<<<g, 256, 0, stream>>>(in, ah, C, H, W);
  };
  // split-K=3 MFMA conv + reduce (BN=128 shapes)
  auto launch_cm4 = [&](const f16* w, const float* b, float* dest, const float* add,
                        int Cin, int Hs, int Ws, int Cout, int lr) {
    dim3 g((NB * Hs * Ws) / 128, Cout / 128, 3);
    conv_mfma4_kernel<<<g, 256, 0, stream>>>(ah, w, part, Cin, Hs, Ws, Cout, Hs * Ws);
    int total4 = (NB * Cout * Hs * Ws) >> 2;
    reduce3_kernel<<<(total4 + 255) / 256, 256, 0, stream>>>(part, b, add, dest,
                                                             Cout, Hs * Ws, lr, total4);
  };
  auto launch_cm2 = [&](const f16* w, const float* b, float* o,
                        int Cin, int Hs, int Ws, int Cout, int lr) {
    dim3 g((NB * Hs * Ws) / 128, Cout / 64);
    conv_mfma2_kernel<<<g, 256, 0, stream>>>(ah, w, b, o, Cin, Hs, Ws, Cout, Hs * Ws, lr);
  };
  auto launch_conv4x = [&](const float* in, const float* w, const float* b, float* out,
                           int Cin, int H, int W, int Cout, int lrelu) {
    dim3 g((W / 16) * (H / 16), Cout / 4, NB);
    conv3x3_kernel<4, 4><<<g, 256, 0, stream>>>(in, w, b, out, Cin, H, W, Cout, lrelu);
  };
  auto launch_conv8x = [&](const float* in, const float* w, const float* b, float* out,
                           int Cin, int H, int W, int Cout, int lrelu) {
    dim3 g((W / 16) * (H / 16), Cout / 8, NB);
    conv3x3_kernel<8, 4><<<g, 256, 0, stream>>>(in, w, b, out, Cin, H, W, Cout, lrelu);
  };
  auto launch_gn = [&](float* xb, const float* g, const float* b, int C, int HW, int G) {
    int SPLIT = 2048 / (G * NB);
    if (SPLIT < 1) SPLIT = 1;
    int len = (C / G) * HW;
    dim3 gs(G * SPLIT, NB);
    gn_stats_kernel<<<gs, 256, 0, stream>>>(xb, gnp, C, HW, G, SPLIT);
    int tot = NB * G;
    gn_combine_kernel<<<(tot + 255) / 256, 256, 0, stream>>>(gnp, gns, SPLIT, len, tot);
    int total4 = (NB * C * HW) >> 2;
    gn_apply_kernel<<<(total4 + 255) / 256, 256, 0, stream>>>(xb, gns, g, b, C, HW, G, total4);
  };
  auto launch_iwt = [&](const float* v, float* out, int C, int H, int W, int c_off, int Ctot) {
    int total = NB * C * H * W;
    iwt_kernel<<<(total + 255) / 256, 256, 0, stream>>>(v, out, C, H, W, c_off, Ctot, total);
  };
  auto launch_copycat = [&](const float* src, float* dst, int C, int HW, int Ctot) {
    int total = NB * C * HW;
    copycat_kernel<<<(total + 255) / 256, 256, 0, stream>>>(src, dst, C, HW, Ctot, total);
  };

  // ---- encoder ----
  launch_wt(x, t1, 3, 128, 128);                                    // w1 (16,12,128,128)
  launch_conv8x(t1, (float*)(base + o_sw1), conv1_b, c1, 12, 128, 128, 16, 1);
  launch_gn(c1, gn1_w, gn1_b, 16, 128 * 128, 2);

  launch_wt(c1, t1, 16, 64, 64);                                    // w2 (16,64,64,64)
  prep_nhwc(t1, 64, 64, 64);
  launch_cm2(pw2, conv2_b, c2, 64, 64, 64, 64, 1);                  // c2
  launch_gn(c2, gn2_w, gn2_b, 64, 64 * 64, 8);

  launch_wt(c2, t1, 64, 32, 32);                                    // w3 (16,256,32,32)
  prep_nhwc(t1, 256, 32, 32);
  launch_cm4(pw3, conv3_b, c3, nullptr, 256, 32, 32, 256, 1);       // c3
  launch_gn(c3, gn3_w, gn3_b, 256, 32 * 32, 32);

  launch_wt(c3, w4, 256, 16, 16);                                   // w4 (16,1024,16,16)

  prep_nhwc(w4, 1024, 16, 16);
  launch_cm4(pw4, conv4_b, t1, nullptr, 1024, 16, 16, 1024, 1);     // c4 -> t1
  launch_gn(t1, gn4_w, gn4_b, 1024, 16 * 16, 128);
  prep_nhwc(t1, 1024, 16, 16);
  launch_cm4(pw4, conv4_b, t2, nullptr, 1024, 16, 16, 1024, 1);     // c5 -> t2
  launch_gn(t2, gn4_w, gn4_b, 1024, 16 * 16, 128);
  prep_nhwc(t2, 1024, 16, 16);
  launch_cm4(pw4, conv4_b, t1, w4, 1024, 16, 16, 1024, 1);          // ic4 = lrelu(c6 + w4) -> t1

  // ---- decoder ----
  launch_copycat(c3, t2, 256, 32 * 32, 512);                        // iw4 -> t2
  launch_iwt(t1, t2, 256, 16, 16, 256, 512);
  prep_nhwc(t2, 512, 32, 32);
  launch_cm4(pwd4, convd4_b, t1, nullptr, 512, 32, 32, 256, 1);     // ic3 -> t1
  launch_gn(t1, gn3_w, gn3_b, 256, 32 * 32, 32);

  launch_copycat(c2, t2, 64, 64 * 64, 128);                         // iw3 -> t2
  launch_iwt(t1, t2, 64, 32, 32, 64, 128);
  prep_nhwc(t2, 128, 64, 64);
  launch_cm2(pwd3, convd3_b, t1, 128, 64, 64, 64, 1);               // ic2 -> t1
  launch_gn(t1, gn2_w, gn2_b, 64, 64 * 64, 8);

  launch_copycat(c1, t2, 16, 128 * 128, 32);                        // iw2 -> t2
  launch_iwt(t1, t2, 16, 64, 64, 16, 32);
  launch_conv8x(t2, (float*)(base + o_swd2), convd2_b, t1, 32, 128, 128, 16, 1);  // ic1
  launch_gn(t1, gn1_w, gn1_b, 16, 128 * 128, 2);

  launch_conv4x(t1, (float*)(base + o_swd1), convd1_b, t2, 16, 128, 128, 12, 1);  // iw1

  launch_iwt(t2, t1, 3, 128, 128, 0, 3);                            // iwt(iw1) (16,3,256,256)

  {  // final 1x1
    int total = NB * 256 * 256;
    final_conv_kernel<<<(total + 255) / 256, 256, 0, stream>>>(t1, (float*)(base + o_swf),
                                                               (float*)d_out, 256 * 256, total);
  }
}

// Round 7
// 1093.546 us; speedup vs baseline: 1.2427x; 1.2427x over previous
//
#include <hip/hip_runtime.h>
#include <math.h>

// ---------------------------------------------------------------------------
// WaveletNet forward. Big convs via f16 MFMA implicit GEMM:
//  - conv_mfma5: 128x128x64 tile (wave 64x64), coalesced m97-style staging,
//    split-K=2 (2 blocks/CU), f16 partials + fused reduce2.
//  - conv_mfma2: 128x64x64 single-buffer for Cout=64 shapes.
// Small convs direct fp32. GN split 3-kernel. N=16 fixed.
// ---------------------------------------------------------------------------

#define NB 16  // batch

typedef _Float16 f16;
typedef _Float16 f16x8 __attribute__((ext_vector_type(8)));
typedef _Float16 f16x4 __attribute__((ext_vector_type(4)));
typedef float f32x4 __attribute__((ext_vector_type(4)));
typedef unsigned int u32;

// async global->LDS 16B: lds dest must be wave-uniform base (+lane*16 by HW)
#define LLDS16(gp, lp)                                                          \
  __builtin_amdgcn_global_load_lds((const __attribute__((address_space(1))) u32*)(const void*)(gp), \
                                   (__attribute__((address_space(3))) u32*)(void*)(lp), 16, 0, 0)

// ---------------- weight standardization (fp32 out, for direct convs) -------
__global__ void ws_kernel(const float* __restrict__ w, float* __restrict__ out, int fan) {
  __shared__ float red[512];
  int o = blockIdx.x;
  const float* wp = w + (size_t)o * fan;
  float s = 0.f, s2 = 0.f;
  for (int i = threadIdx.x; i < fan; i += 256) { float v = wp[i]; s += v; s2 += v * v; }
  red[threadIdx.x] = s; red[256 + threadIdx.x] = s2;
  __syncthreads();
  for (int st = 128; st > 0; st >>= 1) {
    if (threadIdx.x < st) {
      red[threadIdx.x] += red[threadIdx.x + st];
      red[256 + threadIdx.x] += red[256 + threadIdx.x + st];
    }
    __syncthreads();
  }
  float sum = red[0], sumsq = red[256];
  float mean = sum / (float)fan;
  float var = (sumsq - sum * mean) / (float)(fan - 1);
  if (var < 0.f) var = 0.f;
  float inv = 1.0f / (sqrtf(var) + 1e-5f);
  for (int i = threadIdx.x; i < fan; i += 256)
    out[(size_t)o * fan + i] = (wp[i] - mean) * inv;
}

// ---------------- weight standardization + f16 pack [tap][Cout][Cin] --------
__global__ void ws_f16_kernel(const float* __restrict__ w, f16* __restrict__ out,
                              int fan, int Cin, int Cout) {
  __shared__ float red[512];
  int o = blockIdx.x;
  const float* wp = w + (size_t)o * fan;
  float s = 0.f, s2 = 0.f;
  for (int i = threadIdx.x; i < fan; i += 256) { float v = wp[i]; s += v; s2 += v * v; }
  red[threadIdx.x] = s; red[256 + threadIdx.x] = s2;
  __syncthreads();
  for (int st = 128; st > 0; st >>= 1) {
    if (threadIdx.x < st) {
      red[threadIdx.x] += red[threadIdx.x + st];
      red[256 + threadIdx.x] += red[256 + threadIdx.x + st];
    }
    __syncthreads();
  }
  float sum = red[0], sumsq = red[256];
  float mean = sum / (float)fan;
  float var = (sumsq - sum * mean) / (float)(fan - 1);
  if (var < 0.f) var = 0.f;
  float inv = 1.0f / (sqrtf(var) + 1e-5f);
  for (int i = threadIdx.x; i < fan; i += 256) {
    int ci = i / 9, tap = i - ci * 9;
    out[((size_t)tap * Cout + o) * Cin + ci] = (f16)((wp[i] - mean) * inv);
  }
}

// ---------------- zero the 1-px halo of a padded NHWC f16 buffer ------------
__global__ void zero_halo_kernel(f16* __restrict__ buf, int C, int H, int W, int total8) {
  int idx = blockIdx.x * 256 + threadIdx.x;
  if (idx >= total8) return;
  int c8s = C >> 3;
  int c8 = idx % c8s; int t = idx / c8s;
  int P = 2 * (W + 2) + 2 * H;
  int b = t % P; int n = t / P;
  int y, x;
  if (b < W + 2) { y = 0; x = b; }
  else if (b < 2 * (W + 2)) { y = H + 1; x = b - (W + 2); }
  else { int bb = b - 2 * (W + 2); y = 1 + (bb >> 1); x = (bb & 1) ? (W + 1) : 0; }
  size_t a = (((size_t)n * (H + 2) + y) * (W + 2) + x) * C + c8 * 8;
  f16x8 z = {0, 0, 0, 0, 0, 0, 0, 0};
  *(f16x8*)(buf + a) = z;
}

// ---------------- NCHW fp32 -> padded NHWC f16 transpose ----------------
__global__ __launch_bounds__(256) void to_nhwc_pad_kernel(const float* __restrict__ in,
                                                          f16* __restrict__ out,
                                                          int C, int H, int W) {
  __shared__ f16 sm[32][264];
  int HW = H * W;
  int p0 = blockIdx.x * 256, c0 = blockIdx.y * 32, n = blockIdx.z;
  int t = threadIdx.x;
  const float* ip = in + ((size_t)n * C + c0) * HW + p0;
#pragma unroll 8
  for (int r = 0; r < 32; ++r) sm[r][t] = (f16)ip[(size_t)r * HW + t];
  __syncthreads();
#pragma unroll
  for (int i = 0; i < 4; ++i) {
    int c = t + i * 256;
    int pl = c >> 2, cio = (c & 3) * 8;
    f16x8 v;
#pragma unroll
    for (int u = 0; u < 8; ++u) v[u] = sm[cio + u][pl];
    int p = p0 + pl; int y = p / W; int x = p - y * W;
    *(f16x8*)(out + (((size_t)n * (H + 2) + y + 1) * (W + 2) + x + 1) * C + c0 + cio) = v;
  }
}

// ---------------- conv_mfma5: 128x128x64, split-K=2, coalesced staging ------
// A: padded NHWC f16. Wp: [9][Cout][Cin]. part: f16 partials [S][N][Cout][HW].
// 4 waves 2x2, wave tile 64x64 (acc[4][4]); single LDS buffer, 2 barriers/iter.
// Staging identical to mfma2 (r=c>>3 row-major, chunk xor-swizzle) -> coalesced.
__global__ __launch_bounds__(256) void conv_mfma5_kernel(
    const f16* __restrict__ A, const f16* __restrict__ Wp,
    f16* __restrict__ part, int Cin, int H, int W, int Cout, int HW) {
  constexpr int BM = 128, BN = 128, BK = 64;
  __shared__ f16 Asm[BM * BK];  // 16 KB
  __shared__ f16 Bsm[BN * BK];  // 16 KB

  const int tid = threadIdx.x;
  const int w = tid >> 6, lane = tid & 63;
  const int m0 = blockIdx.x * BM;
  const int co0 = blockIdx.y * BN;
  const int Wp2 = W + 2;

  // staging: 1024 16B-chunks each for A and B, 4 issues/thread each
  const f16* gA[4]; const f16* gB[4];
  int lOff[4];
#pragma unroll
  for (int e = 0; e < 4; ++e) {
    int c = e * 256 + tid;
    int r = c >> 3, j = c & 7;
    int jx = j ^ (r & 7);
    int m = m0 + r; int n = m / HW; int p = m - n * HW;
    int y = p / W; int x = p - y * W;
    gA[e] = A + (((size_t)n * (H + 2) + y + 1) * Wp2 + (x + 1)) * Cin + jx * 8;
    gB[e] = Wp + (size_t)(co0 + r) * Cin + jx * 8;
    lOff[e] = (e * 256 + w * 64) * 8;  // wave-uniform base; lane adds lane*16B
  }

  const int wm = w & 1, wn = w >> 1;
  const int lr = lane & 15, quad = lane >> 4;
  int aoffs[4][2], boffs[4][2];
#pragma unroll
  for (int i = 0; i < 4; ++i)
#pragma unroll
    for (int kk = 0; kk < 2; ++kk) {
      int r = wm * 64 + i * 16 + lr;
      int cidx = kk * 4 + quad;
      aoffs[i][kk] = (r * 8 + (cidx ^ (r & 7))) * 8;
      int rb = wn * 64 + i * 16 + lr;
      boffs[i][kk] = (rb * 8 + (cidx ^ (rb & 7))) * 8;
    }

  f32x4 acc[4][4];
#pragma unroll
  for (int i = 0; i < 4; ++i)
#pragma unroll
    for (int j = 0; j < 4; ++j) acc[i][j] = (f32x4){0.f, 0.f, 0.f, 0.f};

  const int kpt = Cin >> 6;                  // BK chunks per tap
  const int nit = (9 * kpt) >> 1;            // split-K = 2
  const size_t bstride = (size_t)Cout * Cin;

  int it0 = blockIdx.z * nit;
  int tap = it0 / kpt, kc = (it0 - tap * kpt) << 6;

  for (int ii = 0; ii < nit; ++ii) {
    int dy = tap / 3 - 1, dx = tap % 3 - 1;
    long offA = ((long)dy * Wp2 + dx) * Cin + kc;
    long offB = (long)tap * bstride + kc;
    __syncthreads();  // prior reads complete before overwrite
#pragma unroll
    for (int e = 0; e < 4; ++e) {
      LLDS16(gA[e] + offA, Asm + lOff[e]);
      LLDS16(gB[e] + offB, Bsm + lOff[e]);
    }
    __syncthreads();  // staging visible (compiler drains vmcnt)

    f16x8 af[4][2], bf[4][2];
#pragma unroll
    for (int i = 0; i < 4; ++i)
#pragma unroll
      for (int kk = 0; kk < 2; ++kk) {
        af[i][kk] = *(const f16x8*)&Asm[aoffs[i][kk]];
        bf[i][kk] = *(const f16x8*)&Bsm[boffs[i][kk]];
      }
#pragma unroll
    for (int kk = 0; kk < 2; ++kk)
#pragma unroll
      for (int i = 0; i < 4; ++i)
#pragma unroll
        for (int j = 0; j < 4; ++j)
          acc[i][j] = __builtin_amdgcn_mfma_f32_16x16x32_f16(af[i][kk], bf[j][kk], acc[i][j], 0, 0, 0);

    kc += 64;
    if (kc == Cin) { kc = 0; ++tap; }
  }

  // epilogue: f16 partial; rows = quad*4+reg, col = lr
  const size_t pbase = (size_t)blockIdx.z * NB * Cout * HW;
#pragma unroll
  for (int i = 0; i < 4; ++i) {
    int mg = m0 + wm * 64 + i * 16 + quad * 4;
    int n = mg / HW, p = mg - n * HW;
#pragma unroll
    for (int j = 0; j < 4; ++j) {
      int co = co0 + wn * 64 + j * 16 + lr;
      f32x4 v = acc[i][j];
      f16x4 h;
#pragma unroll
      for (int r = 0; r < 4; ++r) h[r] = (f16)v[r];
      *(f16x4*)&part[pbase + ((size_t)n * Cout + co) * HW + p] = h;
    }
  }
}

// ---------------- reduce 2 partials + bias (+add) (+lrelu) -> fp32 ----------
__global__ __launch_bounds__(256) void reduce2_kernel(
    const f16* __restrict__ part, const float* __restrict__ bias,
    const float* __restrict__ add, float* __restrict__ out,
    int Cout, int HW, int do_lrelu, int total4) {
  int idx = blockIdx.x * 256 + threadIdx.x;
  if (idx >= total4) return;
  size_t sstride = (size_t)NB * Cout * HW;
  int hw4 = HW >> 2;
  int p4 = idx % hw4; int t = idx / hw4;  // t = n*Cout + c
  int c = t % Cout;
  size_t eoff = (size_t)t * HW + p4 * 4;
  f16x4 a0 = *(const f16x4*)(part + eoff);
  f16x4 a1 = *(const f16x4*)(part + sstride + eoff);
  float b = bias[c];
  f32x4 o;
#pragma unroll
  for (int r = 0; r < 4; ++r) o[r] = (float)a0[r] + (float)a1[r] + b;
  if (add) {
    f32x4 av = *(const f32x4*)(add + eoff);
#pragma unroll
    for (int r = 0; r < 4; ++r) o[r] += av[r];
  }
  if (do_lrelu)
#pragma unroll
    for (int r = 0; r < 4; ++r) o[r] = o[r] > 0.f ? o[r] : 0.2f * o[r];
  *(f32x4*)(out + eoff) = o;
}

// ---------------- conv_mfma2: 128x64x64 single-buffer (Cout=64 shapes) ------
__global__ __launch_bounds__(256) void conv_mfma2_kernel(
    const f16* __restrict__ A, const f16* __restrict__ Wp,
    const float* __restrict__ bias, float* __restrict__ out,
    int Cin, int H, int W, int Cout, int HW, int do_lrelu) {
  constexpr int BM = 128, BN = 64, BK = 64;
  __shared__ f16 Asm[BM * BK];
  __shared__ f16 Bsm[BN * BK];

  const int tid = threadIdx.x;
  const int w = tid >> 6, lane = tid & 63;
  const int m0 = blockIdx.x * BM;
  const int co0 = blockIdx.y * BN;
  const int Wp2 = W + 2;

  const f16* gA[4];
  int lAoff[4];
#pragma unroll
  for (int e = 0; e < 4; ++e) {
    int c = e * 256 + tid;
    int r = c >> 3, j = c & 7;
    int jx = j ^ (r & 7);
    int m = m0 + r; int n = m / HW; int p = m - n * HW;
    int y = p / W; int x = p - y * W;
    gA[e] = A + (((size_t)n * (H + 2) + y + 1) * Wp2 + (x + 1)) * Cin + jx * 8;
    lAoff[e] = (e * 256 + w * 64) * 8;
  }
  const f16* gB[2];
  int lBoff[2];
#pragma unroll
  for (int e = 0; e < 2; ++e) {
    int c = e * 256 + tid;
    int r = c >> 3, j = c & 7;
    int jx = j ^ (r & 7);
    gB[e] = Wp + (size_t)(co0 + r) * Cin + jx * 8;
    lBoff[e] = (e * 256 + w * 64) * 8;
  }

  const int wm = w & 1, wn = w >> 1;
  const int lr = lane & 15, quad = lane >> 4;
  int aoffs[4][2], boffs[2][2];
#pragma unroll
  for (int i = 0; i < 4; ++i)
#pragma unroll
    for (int kk = 0; kk < 2; ++kk) {
      int r = wm * 64 + i * 16 + lr;
      int cidx = kk * 4 + quad;
      aoffs[i][kk] = (r * 8 + (cidx ^ (r & 7))) * 8;
    }
#pragma unroll
  for (int jn = 0; jn < 2; ++jn)
#pragma unroll
    for (int kk = 0; kk < 2; ++kk) {
      int rb = wn * 32 + jn * 16 + lr;
      int cidx = kk * 4 + quad;
      boffs[jn][kk] = (rb * 8 + (cidx ^ (rb & 7))) * 8;
    }

  f32x4 acc[4][2];
#pragma unroll
  for (int i = 0; i < 4; ++i)
#pragma unroll
    for (int jn = 0; jn < 2; ++jn) acc[i][jn] = (f32x4){0.f, 0.f, 0.f, 0.f};

  for (int tap = 0; tap < 9; ++tap) {
    const int dy = tap / 3 - 1, dx = tap % 3 - 1;
    const long tapA = ((long)dy * Wp2 + dx) * Cin;
    const long tapB = (size_t)tap * Cout * Cin;
    for (int kc = 0; kc < Cin; kc += BK) {
      __syncthreads();
#pragma unroll
      for (int e = 0; e < 4; ++e) LLDS16(gA[e] + tapA + kc, Asm + lAoff[e]);
#pragma unroll
      for (int e = 0; e < 2; ++e) LLDS16(gB[e] + tapB + kc, Bsm + lBoff[e]);
      __syncthreads();

      f16x8 af[4][2], bf[2][2];
#pragma unroll
      for (int i = 0; i < 4; ++i)
#pragma unroll
        for (int kk = 0; kk < 2; ++kk) af[i][kk] = *(const f16x8*)&Asm[aoffs[i][kk]];
#pragma unroll
      for (int jn = 0; jn < 2; ++jn)
#pragma unroll
        for (int kk = 0; kk < 2; ++kk) bf[jn][kk] = *(const f16x8*)&Bsm[boffs[jn][kk]];
#pragma unroll
      for (int kk = 0; kk < 2; ++kk)
#pragma unroll
        for (int i = 0; i < 4; ++i)
#pragma unroll
          for (int jn = 0; jn < 2; ++jn)
            acc[i][jn] = __builtin_amdgcn_mfma_f32_16x16x32_f16(af[i][kk], bf[jn][kk], acc[i][jn], 0, 0, 0);
    }
  }

#pragma unroll
  for (int i = 0; i < 4; ++i) {
    int mg = m0 + wm * 64 + i * 16 + quad * 4;
    int n = mg / HW, p = mg - n * HW;
#pragma unroll
    for (int jn = 0; jn < 2; ++jn) {
      int co = co0 + wn * 32 + jn * 16 + lr;
      float b = bias[co];
      f32x4 v = acc[i][jn];
#pragma unroll
      for (int r = 0; r < 4; ++r) {
        float u = v[r] + b;
        v[r] = (do_lrelu && u < 0.f) ? 0.2f * u : u;
      }
      *(f32x4*)&out[((size_t)n * Cout + co) * HW + p] = v;
    }
  }
}

// ---------------- Haar forward (wt) ----------------
__global__ void wt_kernel(const float* __restrict__ in, float* __restrict__ out,
                          int C, int Ho, int Wo, int total) {
  int idx = blockIdx.x * 256 + threadIdx.x;
  if (idx >= total) return;
  int w = idx % Wo; int t = idx / Wo;
  int h = t % Ho; t /= Ho;
  int c = t % C; int n = t / C;
  int Wi = 2 * Wo;
  const float* ip = in + (((size_t)n * C + c) * (2 * Ho) + 2 * h) * Wi + 2 * w;
  float a = ip[0], b = ip[1], cc = ip[Wi], d = ip[Wi + 1];
  size_t cs = (size_t)Ho * Wo;
  float* op = out + (((size_t)n * 4 * C + 4 * c) * Ho + h) * Wo + w;
  op[0]      = 0.25f * (a + b + cc + d);
  op[cs]     = 0.25f * (a + b - cc - d) + 0.5f;
  op[2 * cs] = 0.25f * (a - b + cc - d) + 0.5f;
  op[3 * cs] = 0.25f * (a - b - cc + d) + 0.5f;
}

// ---------------- Haar inverse (iwt) ----------------
__global__ void iwt_kernel(const float* __restrict__ v, float* __restrict__ out,
                           int C, int H, int W, int c_off, int Ctot, int total) {
  int idx = blockIdx.x * 256 + threadIdx.x;
  if (idx >= total) return;
  int w = idx % W; int t = idx / W;
  int h = t % H; t /= H;
  int c = t % C; int n = t / C;
  size_t cs = (size_t)H * W;
  const float* vp = v + (((size_t)n * 4 * C + 4 * c) * H + h) * W + w;
  float v0 = vp[0];
  float v1 = 2.f * vp[cs] - 1.f;
  float v2 = 2.f * vp[2 * cs] - 1.f;
  float v3 = 2.f * vp[3 * cs] - 1.f;
  int Wo = 2 * W;
  float* op = out + (((size_t)n * Ctot + c_off + c) * (2 * H) + 2 * h) * (size_t)Wo + 2 * w;
  op[0]      = v0 + 0.5f * ( v1 + v2 + v3);
  op[1]      = v0 + 0.5f * ( v1 - v2 - v3);
  op[Wo]     = v0 + 0.5f * (-v1 + v2 - v3);
  op[Wo + 1] = v0 + 0.5f * (-v1 - v2 + v3);
}

// ---------------- concat first-part copy ----------------
__global__ void copycat_kernel(const float* __restrict__ src, float* __restrict__ dst,
                               int C, int HW, int Ctot, int total) {
  int idx = blockIdx.x * 256 + threadIdx.x;
  if (idx >= total) return;
  int p = idx % HW; int t = idx / HW;
  int c = t % C; int n = t / C;
  dst[((size_t)n * Ctot + c) * HW + p] = src[idx];
}

// ---------------- direct 3x3 conv (small channel counts) ----------------
template <int CO, int CIC>
__global__ __launch_bounds__(256) void conv3x3_kernel(
    const float* __restrict__ in, const float* __restrict__ wgt,
    const float* __restrict__ bias, float* __restrict__ out,
    int Cin, int H, int W, int Cout, int do_lrelu) {
  __shared__ float sm[CIC][18][18];
  int tiles_x = W >> 4;
  int bt = blockIdx.x;
  int tx0 = (bt % tiles_x) << 4;
  int ty0 = (bt / tiles_x) << 4;
  int co0 = blockIdx.y * CO;
  int n = blockIdx.z;
  int tid = threadIdx.x;
  int lx = tid & 15, ly = tid >> 4;

  float acc[CO];
#pragma unroll
  for (int i = 0; i < CO; i++) acc[i] = 0.f;

  const float* inb = in + (size_t)n * Cin * H * W;

  for (int ci0 = 0; ci0 < Cin; ci0 += CIC) {
    __syncthreads();
    for (int idx = tid; idx < CIC * 324; idx += 256) {
      int ci = idx / 324;
      int r = idx - ci * 324;
      int gy = r / 18, gx = r - gy * 18;
      int iy = ty0 + gy - 1, ix = tx0 + gx - 1;
      float v = 0.f;
      if ((unsigned)iy < (unsigned)H && (unsigned)ix < (unsigned)W)
        v = inb[((size_t)(ci0 + ci)) * H * W + (size_t)iy * W + ix];
      sm[ci][gy][gx] = v;
    }
    __syncthreads();
#pragma unroll
    for (int ci = 0; ci < CIC; ci++) {
      float x00 = sm[ci][ly][lx],     x01 = sm[ci][ly][lx + 1],     x02 = sm[ci][ly][lx + 2];
      float x10 = sm[ci][ly + 1][lx], x11 = sm[ci][ly + 1][lx + 1], x12 = sm[ci][ly + 1][lx + 2];
      float x20 = sm[ci][ly + 2][lx], x21 = sm[ci][ly + 2][lx + 1], x22 = sm[ci][ly + 2][lx + 2];
      const float* wp = wgt + ((size_t)co0 * Cin + (ci0 + ci)) * 9;
#pragma unroll
      for (int co = 0; co < CO; co++) {
        const float* wc = wp + (size_t)co * Cin * 9;
        float a = acc[co];
        a = fmaf(wc[0], x00, a); a = fmaf(wc[1], x01, a); a = fmaf(wc[2], x02, a);
        a = fmaf(wc[3], x10, a); a = fmaf(wc[4], x11, a); a = fmaf(wc[5], x12, a);
        a = fmaf(wc[6], x20, a); a = fmaf(wc[7], x21, a); a = fmaf(wc[8], x22, a);
        acc[co] = a;
      }
    }
  }

  int oy = ty0 + ly, ox = tx0 + lx;
#pragma unroll
  for (int co = 0; co < CO; co++) {
    float v = acc[co] + bias[co0 + co];
    if (do_lrelu) v = v > 0.f ? v : 0.2f * v;
    out[(((size_t)n * Cout + co0 + co) * H + oy) * W + ox] = v;
  }
}

// ---------------- group norm: split 3-kernel ----------------
__global__ __launch_bounds__(256) void gn_stats_kernel(const float* __restrict__ x,
                                                       float* __restrict__ part,
                                                       int C, int HW, int G, int SPLIT) {
  __shared__ float red[512];
  int gs = blockIdx.x;
  int g = gs / SPLIT, s = gs - g * SPLIT;
  int n = blockIdx.y;
  int cpg = C / G;
  int len = cpg * HW;
  int chunk = len / SPLIT;
  size_t base = ((size_t)n * C + (size_t)g * cpg) * HW + (size_t)s * chunk;
  const f32x4* xp = (const f32x4*)(x + base);
  int chunk4 = chunk >> 2;
  float sm = 0.f, s2 = 0.f;
  for (int i = threadIdx.x; i < chunk4; i += 256) {
    f32x4 v = xp[i];
    sm += v.x + v.y + v.z + v.w;
    s2 += v.x * v.x + v.y * v.y + v.z * v.z + v.w * v.w;
  }
  red[threadIdx.x] = sm; red[256 + threadIdx.x] = s2;
  __syncthreads();
  for (int st = 128; st > 0; st >>= 1) {
    if (threadIdx.x < st) {
      red[threadIdx.x] += red[threadIdx.x + st];
      red[256 + threadIdx.x] += red[256 + threadIdx.x + st];
    }
    __syncthreads();
  }
  if (threadIdx.x == 0) {
    int o = ((n * G + g) * SPLIT + s) * 2;
    part[o] = red[0]; part[o + 1] = red[256];
  }
}

__global__ void gn_combine_kernel(const float* __restrict__ part, float* __restrict__ stats,
                                  int SPLIT, int len, int total) {
  int idx = blockIdx.x * 256 + threadIdx.x;
  if (idx >= total) return;
  float s = 0.f, s2 = 0.f;
  for (int i = 0; i < SPLIT; ++i) { s += part[(idx * SPLIT + i) * 2]; s2 += part[(idx * SPLIT + i) * 2 + 1]; }
  float mean = s / (float)len;
  float var = s2 / (float)len - mean * mean;
  if (var < 0.f) var = 0.f;
  stats[idx * 2] = mean;
  stats[idx * 2 + 1] = rsqrtf(var + 1e-5f);
}

__global__ __launch_bounds__(256) void gn_apply_kernel(float* __restrict__ x,
                                                       const float* __restrict__ stats,
                                                       const float* __restrict__ gamma,
                                                       const float* __restrict__ beta,
                                                       int C, int HW, int G, int total4) {
  int idx = blockIdx.x * 256 + threadIdx.x;
  if (idx >= total4) return;
  int hw4 = HW >> 2;
  int p4 = idx % hw4; int t = idx / hw4;
  int c = t % C; int n = t / C;
  int cpg = C / G; int g = c / cpg;
  float mean = stats[(n * G + g) * 2];
  float inv  = stats[(n * G + g) * 2 + 1];
  float ga = gamma[c], be = beta[c];
  f32x4* xp = (f32x4*)(x + ((size_t)t * HW)) + p4;
  f32x4 v = *xp;
#pragma unroll
  for (int r = 0; r < 4; ++r) v[r] = (v[r] - mean) * inv * ga + be;
  *xp = v;
}

// ---------------- final 1x1 conv ----------------
__global__ void final_conv_kernel(const float* __restrict__ in, const float* __restrict__ w,
                                  float* __restrict__ out, int HW, int total) {
  int idx = blockIdx.x * 256 + threadIdx.x;
  if (idx >= total) return;
  int p = idx % HW; int n = idx / HW;
  const float* ip = in + (size_t)n * 3 * HW + p;
  float a = ip[0], b = ip[HW], c = ip[2 * (size_t)HW];
  float* op = out + (size_t)n * 2 * HW + p;
  op[0]  = w[0] * a + w[1] * b + w[2] * c;
  op[HW] = w[3] * a + w[4] * b + w[5] * c;
}

// ---------------------------------------------------------------------------

extern "C" void kernel_launch(void* const* d_in, const int* in_sizes, int n_in,
                              void* d_out, int out_size, void* d_ws, size_t ws_size,
                              hipStream_t stream) {
  const float* x        = (const float*)d_in[0];
  const float* conv1_w  = (const float*)d_in[1];
  const float* conv1_b  = (const float*)d_in[2];
  const float* conv2_w  = (const float*)d_in[3];
  const float* conv2_b  = (const float*)d_in[4];
  const float* conv3_w  = (const float*)d_in[5];
  const float* conv3_b  = (const float*)d_in[6];
  const float* conv4_w  = (const float*)d_in[7];
  const float* conv4_b  = (const float*)d_in[8];
  const float* convd1_w = (const float*)d_in[9];
  const float* convd1_b = (const float*)d_in[10];
  const float* convd2_w = (const float*)d_in[11];
  const float* convd2_b = (const float*)d_in[12];
  const float* convd3_w = (const float*)d_in[13];
  const float* convd3_b = (const float*)d_in[14];
  const float* convd4_w = (const float*)d_in[15];
  const float* convd4_b = (const float*)d_in[16];
  const float* final_w  = (const float*)d_in[17];
  const float* gn1_w = (const float*)d_in[18];
  const float* gn1_b = (const float*)d_in[19];
  const float* gn2_w = (const float*)d_in[20];
  const float* gn2_b = (const float*)d_in[21];
  const float* gn3_w = (const float*)d_in[22];
  const float* gn3_b = (const float*)d_in[23];
  const float* gn4_w = (const float*)d_in[24];
  const float* gn4_b = (const float*)d_in[25];

  char* base = (char*)d_ws;
  size_t off = 0;
  auto allocB = [&](size_t bytes) { size_t o = off; off = (off + bytes + 255) & ~(size_t)255; return o; };

  size_t o_sw1  = allocB(16 * 108 * 4);
  size_t o_swd1 = allocB(12 * 144 * 4);
  size_t o_swd2 = allocB(16 * 288 * 4);
  size_t o_swf  = allocB(6 * 4);
  size_t o_pw2  = allocB((size_t)9 * 64 * 64 * 2);
  size_t o_pw3  = allocB((size_t)9 * 256 * 256 * 2);
  size_t o_pw4  = allocB((size_t)9 * 1024 * 1024 * 2);
  size_t o_pwd3 = allocB((size_t)9 * 64 * 128 * 2);
  size_t o_pwd4 = allocB((size_t)9 * 256 * 512 * 2);
  size_t o_ah   = allocB((size_t)16 * 34 * 34 * 512 * 2);
  size_t o_part = allocB((size_t)2 * NB * 1024 * 256 * 2);  // f16 split-K partials
  size_t o_gnp  = allocB(4096 * 4);
  size_t o_gns  = allocB(4096 * 4);
  size_t o_c1 = allocB((size_t)NB * 16 * 128 * 128 * 4);
  size_t o_c2 = allocB((size_t)NB * 64 * 64 * 64 * 4);
  size_t o_c3 = allocB((size_t)NB * 256 * 32 * 32 * 4);
  size_t o_w4 = allocB((size_t)NB * 1024 * 16 * 16 * 4);
  size_t o_t1 = allocB((size_t)NB * 1024 * 16 * 16 * 4);
  size_t o_t2 = allocB((size_t)NB * 512 * 32 * 32 * 4);

  if (off > ws_size) return;

  float* c1 = (float*)(base + o_c1);
  float* c2 = (float*)(base + o_c2);
  float* c3 = (float*)(base + o_c3);
  float* w4 = (float*)(base + o_w4);
  float* t1 = (float*)(base + o_t1);
  float* t2 = (float*)(base + o_t2);
  f16* ah = (f16*)(base + o_ah);
  f16* part = (f16*)(base + o_part);
  f16* pw2 = (f16*)(base + o_pw2);
  f16* pw3 = (f16*)(base + o_pw3);
  f16* pw4 = (f16*)(base + o_pw4);
  f16* pwd3 = (f16*)(base + o_pwd3);
  f16* pwd4 = (f16*)(base + o_pwd4);
  float* gnp = (float*)(base + o_gnp);
  float* gns = (float*)(base + o_gns);

  // ---- weight prep ----
  ws_kernel<<<16, 256, 0, stream>>>(conv1_w,  (float*)(base + o_sw1),  108);
  ws_kernel<<<12, 256, 0, stream>>>(convd1_w, (float*)(base + o_swd1), 144);
  ws_kernel<<<16, 256, 0, stream>>>(convd2_w, (float*)(base + o_swd2), 288);
  ws_kernel<<<2,  256, 0, stream>>>(final_w,  (float*)(base + o_swf),  3);
  ws_f16_kernel<<<64,   256, 0, stream>>>(conv2_w,  pw2,  576,  64,   64);
  ws_f16_kernel<<<256,  256, 0, stream>>>(conv3_w,  pw3,  2304, 256,  256);
  ws_f16_kernel<<<1024, 256, 0, stream>>>(conv4_w,  pw4,  9216, 1024, 1024);
  ws_f16_kernel<<<64,   256, 0, stream>>>(convd3_w, pwd3, 1152, 128,  64);
  ws_f16_kernel<<<256,  256, 0, stream>>>(convd4_w, pwd4, 4608, 512,  256);

  auto launch_wt = [&](const float* in, float* out, int C, int Ho, int Wo) {
    int total = NB * C * Ho * Wo;
    wt_kernel<<<(total + 255) / 256, 256, 0, stream>>>(in, out, C, Ho, Wo, total);
  };
  auto prep_nhwc = [&](const float* in, int C, int H, int W) {
    int total8 = NB * (2 * (W + 2) + 2 * H) * (C / 8);
    zero_halo_kernel<<<(total8 + 255) / 256, 256, 0, stream>>>(ah, C, H, W, total8);
    dim3 g((H * W) / 256, C / 32, NB);
    to_nhwc_pad_kernel<<<g, 256, 0, stream>>>(in, ah, C, H, W);
  };
  // split-K=2 MFMA conv + fused reduce (Cout>=128 shapes)
  auto launch_cm5 = [&](const f16* w, const float* b, float* dest, const float* add,
                        int Cin, int Hs, int Ws, int Cout, int lr) {
    dim3 g((NB * Hs * Ws) / 128, Cout / 128, 2);
    conv_mfma5_kernel<<<g, 256, 0, stream>>>(ah, w, part, Cin, Hs, Ws, Cout, Hs * Ws);
    int total4 = (NB * Cout * Hs * Ws) >> 2;
    reduce2_kernel<<<(total4 + 255) / 256, 256, 0, stream>>>(part, b, add, dest,
                                                             Cout, Hs * Ws, lr, total4);
  };
  auto launch_cm2 = [&](const f16* w, const float* b, float* o,
                        int Cin, int Hs, int Ws, int Cout, int lr) {
    dim3 g((NB * Hs * Ws) / 128, Cout / 64);
    conv_mfma2_kernel<<<g, 256, 0, stream>>>(ah, w, b, o, Cin, Hs, Ws, Cout, Hs * Ws, lr);
  };
  auto launch_conv4x = [&](const float* in, const float* w, const float* b, float* out,
                           int Cin, int H, int W, int Cout, int lrelu) {
    dim3 g((W / 16) * (H / 16), Cout / 4, NB);
    conv3x3_kernel<4, 4><<<g, 256, 0, stream>>>(in, w, b, out, Cin, H, W, Cout, lrelu);
  };
  auto launch_conv8x = [&](const float* in, const float* w, const float* b, float* out,
                           int Cin, int H, int W, int Cout, int lrelu) {
    dim3 g((W / 16) * (H / 16), Cout / 8, NB);
    conv3x3_kernel<8, 4><<<g, 256, 0, stream>>>(in, w, b, out, Cin, H, W, Cout, lrelu);
  };
  auto launch_gn = [&](float* xb, const float* g, const float* b, int C, int HW, int G) {
    int SPLIT = 2048 / (G * NB);
    if (SPLIT < 1) SPLIT = 1;
    int len = (C / G) * HW;
    dim3 gs(G * SPLIT, NB);
    gn_stats_kernel<<<gs, 256, 0, stream>>>(xb, gnp, C, HW, G, SPLIT);
    int tot = NB * G;
    gn_combine_kernel<<<(tot + 255) / 256, 256, 0, stream>>>(gnp, gns, SPLIT, len, tot);
    int total4 = (NB * C * HW) >> 2;
    gn_apply_kernel<<<(total4 + 255) / 256, 256, 0, stream>>>(xb, gns, g, b, C, HW, G, total4);
  };
  auto launch_iwt = [&](const float* v, float* out, int C, int H, int W, int c_off, int Ctot) {
    int total = NB * C * H * W;
    iwt_kernel<<<(total + 255) / 256, 256, 0, stream>>>(v, out, C, H, W, c_off, Ctot, total);
  };
  auto launch_copycat = [&](const float* src, float* dst, int C, int HW, int Ctot) {
    int total = NB * C * HW;
    copycat_kernel<<<(total + 255) / 256, 256, 0, stream>>>(src, dst, C, HW, Ctot, total);
  };

  // ---- encoder ----
  launch_wt(x, t1, 3, 128, 128);                                    // w1 (16,12,128,128)
  launch_conv8x(t1, (float*)(base + o_sw1), conv1_b, c1, 12, 128, 128, 16, 1);
  launch_gn(c1, gn1_w, gn1_b, 16, 128 * 128, 2);

  launch_wt(c1, t1, 16, 64, 64);                                    // w2 (16,64,64,64)
  prep_nhwc(t1, 64, 64, 64);
  launch_cm2(pw2, conv2_b, c2, 64, 64, 64, 64, 1);                  // c2
  launch_gn(c2, gn2_w, gn2_b, 64, 64 * 64, 8);

  launch_wt(c2, t1, 64, 32, 32);                                    // w3 (16,256,32,32)
  prep_nhwc(t1, 256, 32, 32);
  launch_cm5(pw3, conv3_b, c3, nullptr, 256, 32, 32, 256, 1);       // c3
  launch_gn(c3, gn3_w, gn3_b, 256, 32 * 32, 32);

  launch_wt(c3, w4, 256, 16, 16);                                   // w4 (16,1024,16,16)

  prep_nhwc(w4, 1024, 16, 16);
  launch_cm5(pw4, conv4_b, t1, nullptr, 1024, 16, 16, 1024, 1);     // c4 -> t1
  launch_gn(t1, gn4_w, gn4_b, 1024, 16 * 16, 128);
  prep_nhwc(t1, 1024, 16, 16);
  launch_cm5(pw4, conv4_b, t2, nullptr, 1024, 16, 16, 1024, 1);     // c5 -> t2
  launch_gn(t2, gn4_w, gn4_b, 1024, 16 * 16, 128);
  prep_nhwc(t2, 1024, 16, 16);
  launch_cm5(pw4, conv4_b, t1, w4, 1024, 16, 16, 1024, 1);          // ic4 = lrelu(c6 + w4) -> t1

  // ---- decoder ----
  launch_copycat(c3, t2, 256, 32 * 32, 512);                        // iw4 -> t2
  launch_iwt(t1, t2, 256, 16, 16, 256, 512);
  prep_nhwc(t2, 512, 32, 32);
  launch_cm5(pwd4, convd4_b, t1, nullptr, 512, 32, 32, 256, 1);     // ic3 -> t1
  launch_gn(t1, gn3_w, gn3_b, 256, 32 * 32, 32);

  launch_copycat(c2, t2, 64, 64 * 64, 128);                         // iw3 -> t2
  launch_iwt(t1, t2, 64, 32, 32, 64, 128);
  prep_nhwc(t2, 128, 64, 64);
  launch_cm2(pwd3, convd3_b, t1, 128, 64, 64, 64, 1);               // ic2 -> t1
  launch_gn(t1, gn2_w, gn2_b, 64, 64 * 64, 8);

  launch_copycat(c1, t2, 16, 128 * 128, 32);                        // iw2 -> t2
  launch_iwt(t1, t2, 16, 64, 64, 16, 32);
  launch_conv8x(t2, (float*)(base + o_swd2), convd2_b, t1, 32, 128, 128, 16, 1);  // ic1
  launch_gn(t1, gn1_w, gn1_b, 16, 128 * 128, 2);

  launch_conv4x(t1, (float*)(base + o_swd1), convd1_b, t2, 16, 128, 128, 12, 1);  // iw1

  launch_iwt(t2, t1, 3, 128, 128, 0, 3);                            // iwt(iw1) (16,3,256,256)

  {  // final 1x1
    int total = NB * 256 * 256;
    final_conv_kernel<<<(total + 255) / 256, 256, 0, stream>>>(t1, (float*)(base + o_swf),
                                                               (float*)d_out, 256 * 256, total);
  }
}